// Round 1
// baseline (25.502 us; speedup 1.0000x reference)
//
#include <hip/hip_runtime.h>

// Problem constants (from reference setup_inputs)
static constexpr int N_ROWS = 8192;
static constexpr int D      = 512;
static constexpr int T_LEN  = 2048;
static constexpr float TANH_SCALE = 40.0f;
// Once cumsum > 0.5, tanhf(40*cum) == 1.0f exactly in fp32, so every later
// term of the loss is exactly 0 in the fp32 reference as well -> safe break.
static constexpr float CUT = 0.5f;
static constexpr int KMAX = 64;   // columns of l transposed into ws

// --- pre-pass: lT[t][k] = l[k][t] for t < kmax (tiny: 64*512 elements) ---
__global__ void transpose_l_kernel(const float* __restrict__ l,
                                   float* __restrict__ lT) {
    const int t = blockIdx.x;      // column of l
    const int k = threadIdx.x;     // row of l (0..511)
    lT[t * D + k] = l[k * T_LEN + t];
}

// --- main: one wave per path/row, early-exit on tanh saturation ---
__global__ __launch_bounds__(256) void stopping_loss_kernel(
        const float* __restrict__ ps, const float* __restrict__ pf,
        const float* __restrict__ l,  const float* __restrict__ lT,
        float* __restrict__ partials, int kmax) {
    const int wave = threadIdx.x >> 6;
    const int lane = threadIdx.x & 63;
    const int row  = (blockIdx.x << 2) + wave;

    // ps row resident in registers: element k = c*256 + lane*4 + j, c in {0,1}
    const float4 p0 = *reinterpret_cast<const float4*>(ps + (size_t)row * D + lane * 4);
    const float4 p1 = *reinterpret_cast<const float4*>(ps + (size_t)row * D + 256 + lane * 4);

    const float* __restrict__ pfrow = pf + (size_t)row * T_LEN;

    float cum  = 0.0f;
    float loss = 0.0f;

    for (int t = 0; t < T_LEN; ++t) {
        float dot;
        if (t < kmax) {
            const float* lt = lT + t * D;
            const float4 a0 = *reinterpret_cast<const float4*>(lt + lane * 4);
            const float4 a1 = *reinterpret_cast<const float4*>(lt + 256 + lane * 4);
            dot = p0.x * a0.x + p0.y * a0.y + p0.z * a0.z + p0.w * a0.w
                + p1.x * a1.x + p1.y * a1.y + p1.z * a1.z + p1.w * a1.w;
        } else {
            // Pathological fallback (cumsum still tiny after kmax steps):
            // read the l column directly (strided). Essentially never runs.
            const int b = lane * 4;
            dot  = p0.x * l[(size_t)(b + 0) * T_LEN + t];
            dot += p0.y * l[(size_t)(b + 1) * T_LEN + t];
            dot += p0.z * l[(size_t)(b + 2) * T_LEN + t];
            dot += p0.w * l[(size_t)(b + 3) * T_LEN + t];
            dot += p1.x * l[(size_t)(256 + b + 0) * T_LEN + t];
            dot += p1.y * l[(size_t)(256 + b + 1) * T_LEN + t];
            dot += p1.z * l[(size_t)(256 + b + 2) * T_LEN + t];
            dot += p1.w * l[(size_t)(256 + b + 3) * T_LEN + t];
        }
        // 64-lane butterfly reduce -> identical full dot on every lane
        #pragma unroll
        for (int off = 32; off > 0; off >>= 1)
            dot += __shfl_xor(dot, off, 64);

        cum += dot * dot;
        const float cdf = 0.5f * (1.0f - tanhf(TANH_SCALE * cum));
        if (lane == 0) loss += pfrow[t] * cdf;
        if (cum > CUT) break;     // wave-uniform (reduced value identical)
    }

    __shared__ float acc[4];
    if (lane == 0) acc[wave] = loss;
    __syncthreads();
    if (threadIdx.x == 0)
        partials[blockIdx.x] = (acc[0] + acc[1]) + (acc[2] + acc[3]);
}

// --- deterministic final reduction over block partials ---
__global__ __launch_bounds__(256) void final_reduce_kernel(
        const float* __restrict__ partials, float* __restrict__ out, int nb) {
    float s = 0.0f;
    for (int i = threadIdx.x; i < nb; i += 256) s += partials[i];
    #pragma unroll
    for (int off = 32; off > 0; off >>= 1)
        s += __shfl_xor(s, off, 64);
    __shared__ float acc[4];
    const int wave = threadIdx.x >> 6;
    const int lane = threadIdx.x & 63;
    if (lane == 0) acc[wave] = s;
    __syncthreads();
    if (threadIdx.x == 0)
        out[0] = -((acc[0] + acc[1]) + (acc[2] + acc[3])) / (float)N_ROWS;
}

extern "C" void kernel_launch(void* const* d_in, const int* in_sizes, int n_in,
                              void* d_out, int out_size, void* d_ws, size_t ws_size,
                              hipStream_t stream) {
    const float* l  = (const float*)d_in[0];   // (512, 2048)
    const float* ps = (const float*)d_in[1];   // (8192, 512)
    const float* pf = (const float*)d_in[2];   // (8192, 2048)
    float* out = (float*)d_out;

    const int NB = N_ROWS / 4;                 // 2048 blocks, 4 rows each

    float* lT       = (float*)d_ws;            // KMAX*D floats = 128 KB
    float* partials = lT + (size_t)KMAX * D;   // NB floats = 8 KB
    int kmax = KMAX;
    const size_t need = ((size_t)KMAX * D + NB) * sizeof(float);
    if (ws_size < need) {                      // defensive: tiny ws -> direct l reads
        kmax = 0;
        lT = nullptr;
        partials = (float*)d_ws;
    }

    if (kmax > 0)
        transpose_l_kernel<<<kmax, D, 0, stream>>>(l, lT);
    stopping_loss_kernel<<<NB, 256, 0, stream>>>(ps, pf, l, lT, partials, kmax);
    final_reduce_kernel<<<1, 256, 0, stream>>>(partials, out, NB);
}